// Round 6
// baseline (214.064 us; speedup 1.0000x reference)
//
#include <hip/hip_runtime.h>
#include <stdint.h>

// Problem constants (B, N, H, L) = (4096, 512, 1024, 8)
static constexpr int B_DIM = 4096;
static constexpr int N_DIM = 512;
static constexpr int H_DIM = 1024;
static constexpr int L_DIM = 8;
static constexpr int HL    = H_DIM * L_DIM;   // 8192
static constexpr int KC    = 2 * N_DIM;       // 1024: xcomb/combW row length [lo|hi]

typedef __attribute__((ext_vector_type(8))) short short8;     // 8 bf16 (4 VGPRs)
typedef __attribute__((ext_vector_type(8))) unsigned short u16x8;
typedef __attribute__((ext_vector_type(4))) float f32x4;

// round-to-nearest-even fp32 -> bf16 (bit pattern)
__device__ __forceinline__ uint16_t f2bf(float f) {
  uint32_t u = __float_as_uint(f);
  u += 0x7fffu + ((u >> 16) & 1u);
  return (uint16_t)(u >> 16);
}

__device__ __forceinline__ void stage16(const uint16_t* g, uint16_t* l) {
  __builtin_amdgcn_global_load_lds(
      (const __attribute__((address_space(1))) void*)g,
      (__attribute__((address_space(3))) void*)l, 16, 0, 0);
}

// ---------- fused prep kernel (8 elems/thread, 16B stores) — UNCHANGED ----------
static constexpr int PREP_T0 = HL * N_DIM / 8;       // 524288
static constexpr int PREP_T1 = B_DIM * N_DIM / 8;    // 262144
static constexpr int PREP_T2 = H_DIM * N_DIM / 8;    // 65536

__global__ void prep_kernel(const float* __restrict__ x, const float* __restrict__ beta,
                            const float* __restrict__ W,
                            uint16_t* __restrict__ xcomb, uint16_t* __restrict__ betab,
                            uint16_t* __restrict__ combW) {
  int t = blockIdx.x * 256 + threadIdx.x;
  if (t < PREP_T0) {                           // beta cast
    const f32x4* src = (const f32x4*)(beta + (size_t)t * 8);
    f32x4 a = src[0], b = src[1];
    u16x8 o;
#pragma unroll
    for (int i = 0; i < 4; ++i) { o[i] = f2bf(a[i]); o[4 + i] = f2bf(b[i]); }
    *(u16x8*)(betab + (size_t)t * 8) = o;
    return;
  }
  t -= PREP_T0;
  if (t < PREP_T1) {                           // x | x^2
    int bb = t >> 6, n8 = (t & 63) * 8;
    const f32x4* src = (const f32x4*)(x + (size_t)bb * N_DIM + n8);
    f32x4 a = src[0], b = src[1];
    u16x8 lo, hi;
#pragma unroll
    for (int i = 0; i < 4; ++i) {
      lo[i] = f2bf(a[i]);        lo[4 + i] = f2bf(b[i]);
      hi[i] = f2bf(a[i] * a[i]); hi[4 + i] = f2bf(b[i] * b[i]);
    }
    *(u16x8*)(xcomb + (size_t)bb * KC + n8)         = lo;
    *(u16x8*)(xcomb + (size_t)bb * KC + N_DIM + n8) = hi;
    return;
  }
  t -= PREP_T1;                                // W | -0.5*sum_l beta^2
  int h = t >> 6, n8 = (t & 63) * 8;
  const f32x4* wsrc = (const f32x4*)(W + (size_t)h * N_DIM + n8);
  f32x4 wa = wsrc[0], wb = wsrc[1];
  u16x8 lo;
#pragma unroll
  for (int i = 0; i < 4; ++i) { lo[i] = f2bf(wa[i]); lo[4 + i] = f2bf(wb[i]); }
  *(u16x8*)(combW + (size_t)h * KC + n8) = lo;
  float s[8] = {};
#pragma unroll
  for (int l = 0; l < L_DIM; ++l) {
    const f32x4* bsrc = (const f32x4*)(beta + ((size_t)h * L_DIM + l) * N_DIM + n8);
    f32x4 a = bsrc[0], b = bsrc[1];
#pragma unroll
    for (int i = 0; i < 4; ++i) { s[i] += a[i] * a[i]; s[4 + i] += b[i] * b[i]; }
  }
  u16x8 hi;
#pragma unroll
  for (int i = 0; i < 8; ++i) hi[i] = f2bf(-0.5f * s[i]);
  *(u16x8*)(combW + (size_t)h * KC + N_DIM + n8) = hi;
}

// ---------- fused GEMM v6: 256x256 tile, 1024 threads (16 waves), BK=32 ----------
// v5 -> v6: fit the 128-VGPR budget honestly instead of fighting the allocator.
// Rounds 3-5 proved this toolchain pins the kernel at 128 VGPRs regardless of
// __launch_bounds__/amdgpu_waves_per_eu; with acc+lacc = 160 regs/thread that
// meant ~98 MB scratch (WRITE 117 MB vs 16.4 output) and MfmaUtil 12.6% (=17 us
// of MFMA inside 132 us of stall). 16 waves halve the per-wave tile to 64x64:
// acc[4][4]+lacc[4] = 80 regs/thread — the register profile round 0 compiled
// spill-free at VGPR 124.
//
// Counted-vmcnt pipeline (T3/T4) unchanged: per tile each thread issues
// {W-regload(t+2) + 3 global_load_lds(t+2)} = 4 wave-uniform vmem ops, computes
// tile t, waits vmcnt(4) (drains t+1, leaves t+2 in flight across the raw
// s_barrier). Never vmcnt(0) in the main loop.
//
// Per buffer (48 KB, u16 offsets):
//   Ax  [0, 8192):      256 rows x 32 k of x      (4 chunks/row, slot = c ^ (m&3))
//   Ax2 [8192, 16384):  256 rows x 32 k of x^2
//   Bs  [16384, 24576): 256 betab rows x 32 k
// 3 buffers = 144 KB LDS, 1 block/CU, 16 waves (wm 0..3 x wn 0..3).
// Wave (wm,wn): FM acc = rows wm*64+[0,64) x hl-cols wn*64+[0,64)  (4x4 frags)
// lin: wn parity picks x / x^2 half; h-group (wn>>1)*16+[0,16); partials merged
// in the LDS epilogue (stride-36 f32 red tile), then FM butterfly adds.
static constexpr int S_BUF  = 24576;   // u16 per buffer (48 KB)
static constexpr int OFF_A2 = 8192;
static constexpr int OFF_B  = 16384;

template<bool ODD>
__device__ __forceinline__ void compute_tile(
    const uint16_t* __restrict__ L,
    const int (&offA)[4], const int (&offB)[4], short8 wf,
    f32x4 (&acc)[4][4], f32x4 (&lacc)[4])
{
  short8 bf[4];
#pragma unroll
  for (int j = 0; j < 4; ++j) bf[j] = *(const short8*)(L + offB[j]);
  __builtin_amdgcn_s_setprio(1);
#pragma unroll
  for (int i = 0; i < 4; ++i) {        // FULL unroll: all acc indices static
    short8 a = *(const short8*)(L + offA[i]);
    short8 a2;
    if constexpr (ODD) a2 = *(const short8*)(L + OFF_A2 + offA[i]);
    else               a2 = a;
#pragma unroll
    for (int j = 0; j < 4; ++j)
      acc[i][j] = __builtin_amdgcn_mfma_f32_16x16x32_bf16(a, bf[j], acc[i][j], 0, 0, 0);
    lacc[i] = __builtin_amdgcn_mfma_f32_16x16x32_bf16(a2, wf, lacc[i], 0, 0, 0);
  }
  __builtin_amdgcn_s_setprio(0);
}

__global__ __launch_bounds__(1024) void fm_kernel(
    const uint16_t* __restrict__ xcomb,   // (B, KC)
    const uint16_t* __restrict__ betab,   // (HL, N)
    const uint16_t* __restrict__ combW,   // (H, KC)
    const float* __restrict__ bias,       // (H,)
    float* __restrict__ out)              // (B, H)
{
  __shared__ __align__(16) uint16_t lds[3 * S_BUF];   // 144 KB

  const int tid  = threadIdx.x;
  const int lane = tid & 63;
  const int wave = tid >> 6;            // 0..15
  const int wm = wave >> 2, wn = wave & 3;
  const int fr = lane & 15, quad = lane >> 4;

  // bijective XCD-chunked swizzle: 512 blocks, XCD x gets cids [64x, 64x+64)
  const int bid = blockIdx.x;
  const int cid = (bid & 7) * 64 + (bid >> 3);
  const int bx = cid >> 4, by = cid & 15;
  const int row0 = by * 256, col0 = bx * 256, hcol0 = bx * 32;

  // ---- per-thread staging: chunk s = tid covers A-lo / A-hi / B (1024 each) ----
  const int mA = tid >> 2, cA = (tid & 3) ^ (mA & 3);
  const uint16_t* baseA = xcomb + (size_t)(row0 + mA) * KC + cA * 8;      // x
  const uint16_t* baseB = betab + (size_t)(col0 + mA) * N_DIM + cA * 8;   // betab
  const int dA  = tid * 8;
  const int dA2 = OFF_A2 + tid * 8;
  const int dB  = OFF_B + tid * 8;

  // W fragment source: row hcol0+(wn>>1)*16+fr, half lo/hi by wn parity, cols quad*8..
  const uint16_t* wptr = combW + (size_t)(hcol0 + (wn >> 1) * 16 + fr) * KC
                       + ((wn & 1) ? N_DIM : 0) + quad * 8;

  // ---- per-thread LDS read offsets (tile-invariant, u16 units) ----
  int offA[4], offB[4];
#pragma unroll
  for (int i = 0; i < 4; ++i) {
    int m = wm * 64 + i * 16 + fr;
    offA[i] = (m * 4 + (quad ^ (m & 3))) * 8;
  }
#pragma unroll
  for (int j = 0; j < 4; ++j) {
    int m = wn * 64 + j * 16 + fr;
    offB[j] = OFF_B + (m * 4 + (quad ^ (m & 3))) * 8;
  }

  f32x4 acc[4][4] = {};
  f32x4 lacc[4]   = {};

  auto STAGE = [&](uint16_t* Lp, int kt) {   // 3 global_load_lds per thread
    stage16(baseA + kt, Lp + dA);
    stage16(baseA + N_DIM + kt, Lp + dA2);
    stage16(baseB + kt, Lp + dB);
  };

  // prologue: tiles 0 and 1 in flight (4 vmem each); drain tile 0 only
  short8 wf0 = *(const short8*)(wptr + 0);
  STAGE(lds, 0);
  short8 wf1 = *(const short8*)(wptr + 32);
  STAGE(lds + S_BUF, 32);
  asm volatile("s_waitcnt vmcnt(4)" ::: "memory");
  __builtin_amdgcn_s_barrier();

  int bc = 0;                            // buffer of tile t (t % 3)
  for (int t = 0; t < 14; ++t) {
    int b2 = bc + 2; if (b2 >= 3) b2 -= 3;
    short8 wf2 = *(const short8*)(wptr + (t + 2) * 32);   // W(t+2), 1 vmem
    STAGE(lds + b2 * S_BUF, (t + 2) * 32);                // tile t+2, 3 vmem
    const uint16_t* L = lds + bc * S_BUF;
    if (wn & 1) compute_tile<true >(L, offA, offB, wf0, acc, lacc);
    else        compute_tile<false>(L, offA, offB, wf0, acc, lacc);
    asm volatile("s_waitcnt vmcnt(4)" ::: "memory"); // t+1 drained, t+2 in flight
    __builtin_amdgcn_s_barrier();
    wf0 = wf1; wf1 = wf2;
    bc = (bc == 2) ? 0 : bc + 1;
  }
  { // t = 14: nothing left to stage; then drain tile 15 fully
    const uint16_t* L = lds + 2 * S_BUF;             // bc == 2
    if (wn & 1) compute_tile<true >(L, offA, offB, wf0, acc, lacc);
    else        compute_tile<false>(L, offA, offB, wf0, acc, lacc);
    asm volatile("s_waitcnt vmcnt(0)" ::: "memory");
    __builtin_amdgcn_s_barrier();
  }
  { // t = 15 (buffer 0)
    const uint16_t* L = lds;
    if (wn & 1) compute_tile<true >(L, offA, offB, wf1, acc, lacc);
    else        compute_tile<false>(L, offA, offB, wf1, acc, lacc);
  }
  __syncthreads();   // all buf0 reads done before red overwrites it

  // ---- epilogue: lin partials + FM butterfly meet in LDS, coalesced store ----
  float* red = (float*)lds;              // 256 rows x stride 36 f32 (36 KB < buf0)
  const int hgrp = (wn >> 1) * 16 + fr;
  if (!(wn & 1)) {                       // x-half partial: store
#pragma unroll
    for (int i = 0; i < 4; ++i)
#pragma unroll
      for (int r = 0; r < 4; ++r)
        red[(wm * 64 + i * 16 + quad * 4 + r) * 36 + hgrp] = lacc[i][r];
  }
  __syncthreads();
  if (wn & 1) {                          // x^2-half partial: add
#pragma unroll
    for (int i = 0; i < 4; ++i)
#pragma unroll
      for (int r = 0; r < 4; ++r)
        red[(wm * 64 + i * 16 + quad * 4 + r) * 36 + hgrp] += lacc[i][r];
  }
  __syncthreads();
  // FM: C/D col=lane&15 (hl-local), row=quad*4+r; butterfly over l bits (fr&7)
#pragma unroll
  for (int i = 0; i < 4; ++i)
#pragma unroll
    for (int j = 0; j < 4; ++j) {
      const int hin = wn * 8 + j * 2 + (fr >> 3);
#pragma unroll
      for (int r = 0; r < 4; ++r) {
        float v = acc[i][j][r];
        v = v * v;
        v += __shfl_xor(v, 1);
        v += __shfl_xor(v, 2);
        v += __shfl_xor(v, 4);
        if ((lane & 7) == 0)
          red[(wm * 64 + i * 16 + quad * 4 + r) * 36 + hin] += 0.5f * v;
      }
    }
  __syncthreads();
  {
    const int row = tid >> 2, hb = (tid & 3) * 8;   // 8 floats per thread
    const float* rp = red + row * 36 + hb;
    const float* bp = bias + hcol0 + hb;
    float* op = out + (size_t)(row0 + row) * H_DIM + hcol0 + hb;
    f32x4 v0 = *(const f32x4*)(rp);
    f32x4 v1 = *(const f32x4*)(rp + 4);
    f32x4 b0 = *(const f32x4*)(bp);
    f32x4 b1 = *(const f32x4*)(bp + 4);
    *(f32x4*)(op)     = v0 + b0;
    *(f32x4*)(op + 4) = v1 + b1;
  }
}

extern "C" void kernel_launch(void* const* d_in, const int* in_sizes, int n_in,
                              void* d_out, int out_size, void* d_ws, size_t ws_size,
                              hipStream_t stream) {
  const float* x    = (const float*)d_in[0];  // (4096, 512)
  const float* beta = (const float*)d_in[1];  // (1024, 8, 512)
  const float* W    = (const float*)d_in[2];  // (1024, 512)
  const float* bias = (const float*)d_in[3];  // (1024,)
  float* out = (float*)d_out;                 // (4096, 1024)

  uint16_t* xcomb = (uint16_t*)d_ws;                        // 4096*1024 bf16 = 8 MB
  uint16_t* betab = xcomb + (size_t)B_DIM * KC;             // 8192*512  bf16 = 8 MB
  uint16_t* combW = betab + (size_t)HL * N_DIM;             // 1024*1024 bf16 = 2 MB

  const int prep_threads = PREP_T0 + PREP_T1 + PREP_T2;     // 851968
  prep_kernel<<<prep_threads / 256, 256, 0, stream>>>(x, beta, W, xcomb, betab, combW);

  // 512 blocks (2 rounds/CU), 256x256 tile, 16 waves, counted-vmcnt pipeline
  fm_kernel<<<512, 1024, 0, stream>>>(xcomb, betab, combW, bias, out);
}

// Round 7
// 186.173 us; speedup vs baseline: 1.1498x; 1.1498x over previous
//
#include <hip/hip_runtime.h>
#include <stdint.h>

// Problem constants (B, N, H, L) = (4096, 512, 1024, 8)
static constexpr int B_DIM = 4096;
static constexpr int N_DIM = 512;
static constexpr int H_DIM = 1024;
static constexpr int L_DIM = 8;
static constexpr int HL    = H_DIM * L_DIM;   // 8192
static constexpr int KC    = 2 * N_DIM;       // 1024: xcomb/combW row length [lo|hi]

typedef __attribute__((ext_vector_type(8))) short short8;     // 8 bf16 (4 VGPRs)
typedef __attribute__((ext_vector_type(8))) unsigned short u16x8;
typedef __attribute__((ext_vector_type(4))) float f32x4;

// round-to-nearest-even fp32 -> bf16 (bit pattern)
__device__ __forceinline__ uint16_t f2bf(float f) {
  uint32_t u = __float_as_uint(f);
  u += 0x7fffu + ((u >> 16) & 1u);
  return (uint16_t)(u >> 16);
}

__device__ __forceinline__ void stage16(const uint16_t* g, uint16_t* l) {
  __builtin_amdgcn_global_load_lds(
      (const __attribute__((address_space(1))) void*)g,
      (__attribute__((address_space(3))) void*)l, 16, 0, 0);
}

// ---------- fused prep kernel (8 elems/thread, 16B stores) — UNCHANGED ----------
static constexpr int PREP_T0 = HL * N_DIM / 8;       // 524288
static constexpr int PREP_T1 = B_DIM * N_DIM / 8;    // 262144
static constexpr int PREP_T2 = H_DIM * N_DIM / 8;    // 65536

__global__ void prep_kernel(const float* __restrict__ x, const float* __restrict__ beta,
                            const float* __restrict__ W,
                            uint16_t* __restrict__ xcomb, uint16_t* __restrict__ betab,
                            uint16_t* __restrict__ combW) {
  int t = blockIdx.x * 256 + threadIdx.x;
  if (t < PREP_T0) {                           // beta cast
    const f32x4* src = (const f32x4*)(beta + (size_t)t * 8);
    f32x4 a = src[0], b = src[1];
    u16x8 o;
#pragma unroll
    for (int i = 0; i < 4; ++i) { o[i] = f2bf(a[i]); o[4 + i] = f2bf(b[i]); }
    *(u16x8*)(betab + (size_t)t * 8) = o;
    return;
  }
  t -= PREP_T0;
  if (t < PREP_T1) {                           // x | x^2
    int bb = t >> 6, n8 = (t & 63) * 8;
    const f32x4* src = (const f32x4*)(x + (size_t)bb * N_DIM + n8);
    f32x4 a = src[0], b = src[1];
    u16x8 lo, hi;
#pragma unroll
    for (int i = 0; i < 4; ++i) {
      lo[i] = f2bf(a[i]);        lo[4 + i] = f2bf(b[i]);
      hi[i] = f2bf(a[i] * a[i]); hi[4 + i] = f2bf(b[i] * b[i]);
    }
    *(u16x8*)(xcomb + (size_t)bb * KC + n8)         = lo;
    *(u16x8*)(xcomb + (size_t)bb * KC + N_DIM + n8) = hi;
    return;
  }
  t -= PREP_T1;                                // W | -0.5*sum_l beta^2
  int h = t >> 6, n8 = (t & 63) * 8;
  const f32x4* wsrc = (const f32x4*)(W + (size_t)h * N_DIM + n8);
  f32x4 wa = wsrc[0], wb = wsrc[1];
  u16x8 lo;
#pragma unroll
  for (int i = 0; i < 4; ++i) { lo[i] = f2bf(wa[i]); lo[4 + i] = f2bf(wb[i]); }
  *(u16x8*)(combW + (size_t)h * KC + n8) = lo;
  float s[8] = {};
#pragma unroll
  for (int l = 0; l < L_DIM; ++l) {
    const f32x4* bsrc = (const f32x4*)(beta + ((size_t)h * L_DIM + l) * N_DIM + n8);
    f32x4 a = bsrc[0], b = bsrc[1];
#pragma unroll
    for (int i = 0; i < 4; ++i) { s[i] += a[i] * a[i]; s[4 + i] += b[i] * b[i]; }
  }
  u16x8 hi;
#pragma unroll
  for (int i = 0; i < 8; ++i) hi[i] = f2bf(-0.5f * s[i]);
  *(u16x8*)(combW + (size_t)h * KC + N_DIM + n8) = hi;
}

// ---------- fused GEMM v7: 128x128 tile, 256 threads (4 waves), BK=32 ----------
// Lesson of rounds 3-6: the allocator's VGPR budget is workgroup-size-determined
// and immovable (512thr->128, 1024thr->64, attributes ignored, 3 bit-identical
// binaries). Only the 256-thread/80-acc-reg profile (round 0, VGPR 124) is
// proven spill-free. v7 keeps that register profile and adds the counted-vmcnt
// triple-buffer pipeline: per tile each thread issues 7 wave-uniform
// global_load_lds (2 A-lo, 2 A-hi, 2 B, 1 W), computes tile t, waits vmcnt(7)
// (drains t+1, leaves t+2's 7 in flight across the raw s_barrier). Never
// vmcnt(0) in the main loop.
//
// Per buffer (26 KB, u16 offsets):
//   Ax  [0,4096):        128 rows x 32 k of x    (4 chunks/row)
//   Ax2 [4096,8192):     128 rows x 32 k of x^2
//   Bs  [8192,12288):    128 betab rows x 32 k
//   Wc  [12288,13312):   16 h x 8 chunks (lo k0..3 | hi k4..7)
// chunk swizzle: slot = cp ^ ((m + (m>>2)) & 3)  -> 2-way bank access (free),
// vs old cp^(m&3) which was 4-way (1.58x). 3 buffers = 78 KB -> 2 blocks/CU.
// Wave (wm,wn), wm,wn in {0,1}: FM acc rows wm*64+[0,64) x hl-cols wn*64+[0,64).
// lin: wn=0 -> x-half (W), wn=1 -> x^2-half (-0.5*sum beta^2); all 16 h via fr.
static constexpr int S_BUF  = 13312;   // u16 per buffer (26 KB)
static constexpr int OFF_A2 = 4096;
static constexpr int OFF_B  = 8192;
static constexpr int OFF_W  = 12288;

template<bool ODD>
__device__ __forceinline__ void compute_tile(
    const uint16_t* __restrict__ L,
    const int (&offA)[4], const int (&offB)[4], int offW,
    f32x4 (&acc)[4][4], f32x4 (&lacc)[4])
{
  short8 bf[4];
#pragma unroll
  for (int j = 0; j < 4; ++j) bf[j] = *(const short8*)(L + offB[j]);
  short8 wf = *(const short8*)(L + offW);
  __builtin_amdgcn_s_setprio(1);
#pragma unroll
  for (int i = 0; i < 4; ++i) {        // full unroll: all acc indices static
    short8 a = *(const short8*)(L + offA[i]);
    short8 a2;
    if constexpr (ODD) a2 = *(const short8*)(L + OFF_A2 + offA[i]);
    else               a2 = a;
#pragma unroll
    for (int j = 0; j < 4; ++j)
      acc[i][j] = __builtin_amdgcn_mfma_f32_16x16x32_bf16(a, bf[j], acc[i][j], 0, 0, 0);
    lacc[i] = __builtin_amdgcn_mfma_f32_16x16x32_bf16(a2, wf, lacc[i], 0, 0, 0);
  }
  __builtin_amdgcn_s_setprio(0);
}

__global__ __launch_bounds__(256) void fm_kernel(
    const uint16_t* __restrict__ xcomb,   // (B, KC)
    const uint16_t* __restrict__ betab,   // (HL, N)
    const uint16_t* __restrict__ combW,   // (H, KC)
    const float* __restrict__ bias,       // (H,)
    float* __restrict__ out)              // (B, H)
{
  __shared__ __align__(16) uint16_t lds[3 * S_BUF];   // 78 KB

  const int tid  = threadIdx.x;
  const int lane = tid & 63;
  const int wave = tid >> 6;            // 0..3
  const int wm = wave >> 1, wn = wave & 1;
  const int fr = lane & 15, quad = lane >> 4;

  // bijective XCD-chunked swizzle: 2048 blocks, XCD x gets cids [256x, 256x+256)
  const int bid = blockIdx.x;
  const int cid = (bid & 7) * 256 + (bid >> 3);
  const int bx = cid >> 5, by = cid & 31;         // 64 x 32
  const int row0 = by * 128, col0 = bx * 128, hcol0 = bx * 16;

  // ---- per-thread staging sources (pre-swizzled global) + LDS dest offsets ----
  const int s0 = tid, s1 = tid + 256;
  const int m0 = s0 >> 2, c0 = (s0 & 3) ^ ((m0 + (m0 >> 2)) & 3);
  const int m1 = s1 >> 2, c1 = (s1 & 3) ^ ((m1 + (m1 >> 2)) & 3);
  const uint16_t* baseA0 = xcomb + (size_t)(row0 + m0) * KC + c0 * 8;
  const uint16_t* baseA1 = xcomb + (size_t)(row0 + m1) * KC + c1 * 8;
  const uint16_t* baseB0 = betab + (size_t)(col0 + m0) * N_DIM + c0 * 8;
  const uint16_t* baseB1 = betab + (size_t)(col0 + m1) * N_DIM + c1 * 8;
  const int d0 = s0 * 8, d1 = s1 * 8;
  // W: 128 chunks (16 h x 8), staged duplicated by both half-blocks (same data)
  const int sW = tid & 127;
  const int mW = sW >> 3, cpW = sW & 7, cW = cpW ^ (mW & 7);
  const uint16_t* baseW = combW + (size_t)(hcol0 + mW) * KC
                        + (cW < 4 ? cW * 8 : N_DIM + (cW - 4) * 8);
  const int dW = sW * 8;

  // ---- per-thread LDS read offsets (tile-invariant, u16 units) ----
  int offA[4], offB[4], offW_;
#pragma unroll
  for (int i = 0; i < 4; ++i) {
    int m = wm * 64 + i * 16 + fr;
    offA[i] = (m * 4 + (quad ^ ((m + (m >> 2)) & 3))) * 8;
  }
#pragma unroll
  for (int j = 0; j < 4; ++j) {
    int m = wn * 64 + j * 16 + fr;
    offB[j] = OFF_B + (m * 4 + (quad ^ ((m + (m >> 2)) & 3))) * 8;
  }
  offW_ = OFF_W + (fr * 8 + ((wn * 4 + quad) ^ (fr & 7))) * 8;

  f32x4 acc[4][4] = {};
  f32x4 lacc[4]   = {};

  auto STAGE = [&](uint16_t* Lp, int kt) {   // 7 global_load_lds per thread
    stage16(baseA0 + kt, Lp + d0);
    stage16(baseA1 + kt, Lp + d1);
    stage16(baseA0 + N_DIM + kt, Lp + OFF_A2 + d0);
    stage16(baseA1 + N_DIM + kt, Lp + OFF_A2 + d1);
    stage16(baseB0 + kt, Lp + OFF_B + d0);
    stage16(baseB1 + kt, Lp + OFF_B + d1);
    stage16(baseW + kt, Lp + OFF_W + dW);
  };

  // prologue: tiles 0 and 1 in flight (7 vmem each); drain tile 0 only
  STAGE(lds, 0);
  STAGE(lds + S_BUF, 32);
  asm volatile("s_waitcnt vmcnt(7)" ::: "memory");
  __builtin_amdgcn_s_barrier();

  int bc = 0;                            // buffer of tile t (t % 3)
  for (int t = 0; t < 14; ++t) {
    int b2 = bc + 2; if (b2 >= 3) b2 -= 3;
    STAGE(lds + b2 * S_BUF, (t + 2) * 32);           // tile t+2
    const uint16_t* L = lds + bc * S_BUF;
    if (wn) compute_tile<true >(L, offA, offB, offW_, acc, lacc);
    else    compute_tile<false>(L, offA, offB, offW_, acc, lacc);
    asm volatile("s_waitcnt vmcnt(7)" ::: "memory"); // t+1 drained, t+2 in flight
    __builtin_amdgcn_s_barrier();
    bc = (bc == 2) ? 0 : bc + 1;
  }
  { // t = 14: nothing left to stage; drain tile 15 fully
    const uint16_t* L = lds + 2 * S_BUF;             // bc == 2
    if (wn) compute_tile<true >(L, offA, offB, offW_, acc, lacc);
    else    compute_tile<false>(L, offA, offB, offW_, acc, lacc);
    asm volatile("s_waitcnt vmcnt(0)" ::: "memory");
    __builtin_amdgcn_s_barrier();
  }
  { // t = 15 (buffer 0)
    const uint16_t* L = lds;
    if (wn) compute_tile<true >(L, offA, offB, offW_, acc, lacc);
    else    compute_tile<false>(L, offA, offB, offW_, acc, lacc);
  }
  __syncthreads();   // all buf0 reads done before red overwrites it

  // ---- epilogue: lin partials + FM butterfly meet in LDS, coalesced store ----
  float* red = (float*)lds;              // 128 rows x stride 20 f32 = 10 KB
  if (!wn) {                             // x-half partial: store
#pragma unroll
    for (int i = 0; i < 4; ++i)
#pragma unroll
      for (int r = 0; r < 4; ++r)
        red[(wm * 64 + i * 16 + quad * 4 + r) * 20 + fr] = lacc[i][r];
  }
  __syncthreads();
  if (wn) {                              // x^2-half partial: add
#pragma unroll
    for (int i = 0; i < 4; ++i)
#pragma unroll
      for (int r = 0; r < 4; ++r)
        red[(wm * 64 + i * 16 + quad * 4 + r) * 20 + fr] += lacc[i][r];
  }
  __syncthreads();
  // FM: C/D col=lane&15 (hl-local), row=quad*4+r; butterfly over l bits (fr&7)
#pragma unroll
  for (int i = 0; i < 4; ++i)
#pragma unroll
    for (int j = 0; j < 4; ++j) {
      const int hin = wn * 8 + j * 2 + (fr >> 3);
#pragma unroll
      for (int r = 0; r < 4; ++r) {
        float v = acc[i][j][r];
        v = v * v;
        v += __shfl_xor(v, 1);
        v += __shfl_xor(v, 2);
        v += __shfl_xor(v, 4);
        if ((lane & 7) == 0)
          red[(wm * 64 + i * 16 + quad * 4 + r) * 20 + hin] += 0.5f * v;
      }
    }
  __syncthreads();
  {
    const int row = tid >> 1, hb = (tid & 1) * 8;   // 8 floats per thread
    const float* rp = red + row * 20 + hb;
    const float* bp = bias + hcol0 + hb;
    float* op = out + (size_t)(row0 + row) * H_DIM + hcol0 + hb;
    f32x4 v0 = *(const f32x4*)(rp);
    f32x4 v1 = *(const f32x4*)(rp + 4);
    f32x4 b0 = *(const f32x4*)(bp);
    f32x4 b1 = *(const f32x4*)(bp + 4);
    *(f32x4*)(op)     = v0 + b0;
    *(f32x4*)(op + 4) = v1 + b1;
  }
}

extern "C" void kernel_launch(void* const* d_in, const int* in_sizes, int n_in,
                              void* d_out, int out_size, void* d_ws, size_t ws_size,
                              hipStream_t stream) {
  const float* x    = (const float*)d_in[0];  // (4096, 512)
  const float* beta = (const float*)d_in[1];  // (1024, 8, 512)
  const float* W    = (const float*)d_in[2];  // (1024, 512)
  const float* bias = (const float*)d_in[3];  // (1024,)
  float* out = (float*)d_out;                 // (4096, 1024)

  uint16_t* xcomb = (uint16_t*)d_ws;                        // 4096*1024 bf16 = 8 MB
  uint16_t* betab = xcomb + (size_t)B_DIM * KC;             // 8192*512  bf16 = 8 MB
  uint16_t* combW = betab + (size_t)HL * N_DIM;             // 1024*1024 bf16 = 2 MB

  const int prep_threads = PREP_T0 + PREP_T1 + PREP_T2;     // 851968
  prep_kernel<<<prep_threads / 256, 256, 0, stream>>>(x, beta, W, xcomb, betab, combW);

  // 2048 blocks (64 bx x 32 by), 128x128 tile, 4 waves, counted-vmcnt pipeline
  fm_kernel<<<2048, 256, 0, stream>>>(xcomb, betab, combW, bias, out);
}

// Round 8
// 172.928 us; speedup vs baseline: 1.2379x; 1.0766x over previous
//
#include <hip/hip_runtime.h>
#include <stdint.h>

// Problem constants (B, N, H, L) = (4096, 512, 1024, 8)
static constexpr int B_DIM = 4096;
static constexpr int N_DIM = 512;
static constexpr int H_DIM = 1024;
static constexpr int L_DIM = 8;
static constexpr int HL    = H_DIM * L_DIM;   // 8192
static constexpr int KC    = 2 * N_DIM;       // 1024: combW row length [W | -0.5*sum beta^2]

typedef __attribute__((ext_vector_type(8))) short short8;     // 8 bf16 (4 VGPRs)
typedef __attribute__((ext_vector_type(8))) unsigned short u16x8;
typedef __attribute__((ext_vector_type(4))) float f32x4;
typedef __attribute__((ext_vector_type(4))) unsigned int u32x4;

// round-to-nearest-even fp32 -> bf16 (bit pattern)
__device__ __forceinline__ uint16_t f2bf(float f) {
  uint32_t u = __float_as_uint(f);
  u += 0x7fffu + ((u >> 16) & 1u);
  return (uint16_t)(u >> 16);
}

__device__ __forceinline__ void stage16(const uint16_t* g, uint16_t* l) {
  __builtin_amdgcn_global_load_lds(
      (const __attribute__((address_space(1))) void*)g,
      (__attribute__((address_space(3))) void*)l, 16, 0, 0);
}

// square a bf16x8 fragment in-register -> bf16x8 (v_cvt_pk_bf16_f32 packs pairs)
__device__ __forceinline__ short8 sq8(short8 a) {
  u32x4 r;
#pragma unroll
  for (int p = 0; p < 4; ++p) {
    float f0 = __uint_as_float(((uint32_t)(uint16_t)a[2 * p])     << 16);
    float f1 = __uint_as_float(((uint32_t)(uint16_t)a[2 * p + 1]) << 16);
    float s0 = f0 * f0, s1 = f1 * f1;
    uint32_t pk;
    asm("v_cvt_pk_bf16_f32 %0, %1, %2" : "=v"(pk) : "v"(s0), "v"(s1));
    r[p] = pk;
  }
  return __builtin_bit_cast(short8, r);
}

// ---------- fused prep kernel ----------
// region 0: betab = bf16(beta)                                (HL*N/8 threads)
// region 1: xonly[b,0:512] = bf16(x)                          (B*N/8)   [x^2 now in-reg]
// region 2: combW[h,0:512]=bf16(W), [512:1024]=bf16(-0.5*sum_l beta^2)  (H*N/8)
static constexpr int PREP_T0 = HL * N_DIM / 8;       // 524288
static constexpr int PREP_T1 = B_DIM * N_DIM / 8;    // 262144
static constexpr int PREP_T2 = H_DIM * N_DIM / 8;    // 65536

__global__ void prep_kernel(const float* __restrict__ x, const float* __restrict__ beta,
                            const float* __restrict__ W,
                            uint16_t* __restrict__ xonly, uint16_t* __restrict__ betab,
                            uint16_t* __restrict__ combW) {
  int t = blockIdx.x * 256 + threadIdx.x;
  if (t < PREP_T0) {                           // beta cast
    const f32x4* src = (const f32x4*)(beta + (size_t)t * 8);
    f32x4 a = src[0], b = src[1];
    u16x8 o;
#pragma unroll
    for (int i = 0; i < 4; ++i) { o[i] = f2bf(a[i]); o[4 + i] = f2bf(b[i]); }
    *(u16x8*)(betab + (size_t)t * 8) = o;
    return;
  }
  t -= PREP_T0;
  if (t < PREP_T1) {                           // x only
    int bb = t >> 6, n8 = (t & 63) * 8;
    const f32x4* src = (const f32x4*)(x + (size_t)bb * N_DIM + n8);
    f32x4 a = src[0], b = src[1];
    u16x8 lo;
#pragma unroll
    for (int i = 0; i < 4; ++i) { lo[i] = f2bf(a[i]); lo[4 + i] = f2bf(b[i]); }
    *(u16x8*)(xonly + (size_t)bb * N_DIM + n8) = lo;
    return;
  }
  t -= PREP_T1;                                // W | -0.5*sum_l beta^2
  int h = t >> 6, n8 = (t & 63) * 8;
  const f32x4* wsrc = (const f32x4*)(W + (size_t)h * N_DIM + n8);
  f32x4 wa = wsrc[0], wb = wsrc[1];
  u16x8 lo;
#pragma unroll
  for (int i = 0; i < 4; ++i) { lo[i] = f2bf(wa[i]); lo[4 + i] = f2bf(wb[i]); }
  *(u16x8*)(combW + (size_t)h * KC + n8) = lo;
  float s[8] = {};
#pragma unroll
  for (int l = 0; l < L_DIM; ++l) {
    const f32x4* bsrc = (const f32x4*)(beta + ((size_t)h * L_DIM + l) * N_DIM + n8);
    f32x4 a = bsrc[0], b = bsrc[1];
#pragma unroll
    for (int i = 0; i < 4; ++i) { s[i] += a[i] * a[i]; s[4 + i] += b[i] * b[i]; }
  }
  u16x8 hi;
#pragma unroll
  for (int i = 0; i < 8; ++i) hi[i] = f2bf(-0.5f * s[i]);
  *(u16x8*)(combW + (size_t)h * KC + N_DIM + n8) = hi;
}

// ---------- fused GEMM v8: 128x128 tile, 256 threads, BK=32, double-buffered ----------
// v7 post-mortem: spill fixed (WRITE 16.7 MB) but triple-buffer cost a block/CU
// (2 vs r0's 3) and counted-vmcnt couldn't compensate -> 112 us vs r0's 87.
// m114 mechanism: cross-block wave overlap hides drains; occupancy wins.
// v8: (1) x^2 computed IN-REGISTER from the already-loaded x fragment (sq8) --
//     deletes the Ax2 LDS plane, 2 gload_lds/thread/step and ~256 MB of fetch;
// (2) buffer = A 8K + B 8K + W 2K = 18 KB, double-buffered = 36 KB -> 4 blocks/CU
//     (16 waves/CU, 2x r0);
// (3) 2-phase pipeline, ONE __syncthreads per K-step: issue stage(t+1) into the
//     other buffer, compute(t), syncthreads (its implicit vmcnt(0) is the drain,
//     covered by the compute phase + 4 resident blocks).
// chunk swizzle slot = cp ^ ((m + (m>>2)) & 3): 16-lane column reads touch each
// bank pair exactly twice (2-way = free, m136).
static constexpr int S_BUF = 9216;    // u16 per buffer (18 KB)
static constexpr int OFF_B = 4096;
static constexpr int OFF_W = 8192;

template<bool ODD>
__device__ __forceinline__ void compute_tile(
    const uint16_t* __restrict__ L,
    const int (&offA)[4], const int (&offB)[4], int offW,
    f32x4 (&acc)[4][4], f32x4 (&lacc)[4])
{
  short8 bf[4];
#pragma unroll
  for (int j = 0; j < 4; ++j) bf[j] = *(const short8*)(L + offB[j]);
  short8 wf = *(const short8*)(L + offW);
  __builtin_amdgcn_s_setprio(1);
#pragma unroll
  for (int i = 0; i < 4; ++i) {        // full unroll: all acc indices static
    short8 a = *(const short8*)(L + offA[i]);
#pragma unroll
    for (int j = 0; j < 4; ++j)
      acc[i][j] = __builtin_amdgcn_mfma_f32_16x16x32_bf16(a, bf[j], acc[i][j], 0, 0, 0);
    short8 al;
    if constexpr (ODD) al = sq8(a);    // x^2 fragment, no LDS/global traffic
    else               al = a;
    lacc[i] = __builtin_amdgcn_mfma_f32_16x16x32_bf16(al, wf, lacc[i], 0, 0, 0);
  }
  __builtin_amdgcn_s_setprio(0);
}

__global__ __launch_bounds__(256) void fm_kernel(
    const uint16_t* __restrict__ xonly,   // (B, N)
    const uint16_t* __restrict__ betab,   // (HL, N)
    const uint16_t* __restrict__ combW,   // (H, KC)
    const float* __restrict__ bias,       // (H,)
    float* __restrict__ out)              // (B, H)
{
  __shared__ __align__(16) uint16_t lds[2 * S_BUF];   // 36 KB -> 4 blocks/CU

  const int tid  = threadIdx.x;
  const int lane = tid & 63;
  const int wave = tid >> 6;            // 0..3
  const int wm = wave >> 1, wn = wave & 1;
  const int fr = lane & 15, quad = lane >> 4;

  // bijective XCD-chunked swizzle: 2048 blocks, XCD x gets cids [256x, 256x+256)
  // concurrent 128 blocks/XCD = 4 bx (B panels L2-hot) x 32 by (A shared by bx)
  const int bid = blockIdx.x;
  const int cid = (bid & 7) * 256 + (bid >> 3);
  const int bx = cid >> 5, by = cid & 31;         // 64 x 32
  const int row0 = by * 128, col0 = bx * 128, hcol0 = bx * 16;

  // ---- per-thread staging sources (pre-swizzled global) + LDS dest offsets ----
  const int s0 = tid, s1 = tid + 256;
  const int m0 = s0 >> 2, c0 = (s0 & 3) ^ ((m0 + (m0 >> 2)) & 3);
  const int m1 = s1 >> 2, c1 = (s1 & 3) ^ ((m1 + (m1 >> 2)) & 3);
  const uint16_t* baseA0 = xonly + (size_t)(row0 + m0) * N_DIM + c0 * 8;
  const uint16_t* baseA1 = xonly + (size_t)(row0 + m1) * N_DIM + c1 * 8;
  const uint16_t* baseB0 = betab + (size_t)(col0 + m0) * N_DIM + c0 * 8;
  const uint16_t* baseB1 = betab + (size_t)(col0 + m1) * N_DIM + c1 * 8;
  const int d0 = s0 * 8;                       // A dests: d0, d0+2048
  // W: 128 chunks (16 h x 8: lo k0..3 | hi k4..7), duplicated by both half-blocks
  const int sW = tid & 127;
  const int mW = sW >> 3, cpW = sW & 7, cW = cpW ^ (mW & 7);
  const uint16_t* baseW = combW + (size_t)(hcol0 + mW) * KC
                        + (cW < 4 ? cW * 8 : N_DIM + (cW - 4) * 8);
  const int dW = OFF_W + sW * 8;

  // ---- per-thread LDS read offsets (tile-invariant, u16 units) ----
  int offA[4], offB[4], offW_;
#pragma unroll
  for (int i = 0; i < 4; ++i) {
    int m = wm * 64 + i * 16 + fr;
    offA[i] = (m * 4 + (quad ^ ((m + (m >> 2)) & 3))) * 8;
  }
#pragma unroll
  for (int j = 0; j < 4; ++j) {
    int m = wn * 64 + j * 16 + fr;
    offB[j] = OFF_B + (m * 4 + (quad ^ ((m + (m >> 2)) & 3))) * 8;
  }
  offW_ = OFF_W + (fr * 8 + ((wn * 4 + quad) ^ (fr & 7))) * 8;

  f32x4 acc[4][4] = {};
  f32x4 lacc[4]   = {};

  auto STAGE = [&](uint16_t* Lp, int kt) {   // 5 global_load_lds per thread
    stage16(baseA0 + kt, Lp + d0);
    stage16(baseA1 + kt, Lp + d0 + 2048);
    stage16(baseB0 + kt, Lp + OFF_B + d0);
    stage16(baseB1 + kt, Lp + OFF_B + d0 + 2048);
    stage16(baseW + kt, Lp + dW);
  };

  STAGE(lds, 0);
  __syncthreads();                       // drains vmcnt: tile 0 ready

  for (int t = 0; t < 15; ++t) {
    uint16_t* nxt       = lds + ((t & 1) ^ 1) * S_BUF;
    const uint16_t* cur = lds + (t & 1) * S_BUF;
    STAGE(nxt, (t + 1) * 32);            // overlap next-tile staging with compute
    if (wn) compute_tile<true >(cur, offA, offB, offW_, acc, lacc);
    else    compute_tile<false>(cur, offA, offB, offW_, acc, lacc);
    __syncthreads();                     // drain stage(t+1) + LDS ordering
  }
  { // t = 15 (buffer 1), nothing left to stage
    const uint16_t* cur = lds + S_BUF;
    if (wn) compute_tile<true >(cur, offA, offB, offW_, acc, lacc);
    else    compute_tile<false>(cur, offA, offB, offW_, acc, lacc);
  }
  __syncthreads();   // all LDS reads done before red overwrites buffer 0

  // ---- epilogue: lin partials + FM butterfly meet in LDS, coalesced store ----
  float* red = (float*)lds;              // 128 rows x stride 20 f32 = 10 KB
  if (!wn) {                             // x-half partial: store
#pragma unroll
    for (int i = 0; i < 4; ++i)
#pragma unroll
      for (int r = 0; r < 4; ++r)
        red[(wm * 64 + i * 16 + quad * 4 + r) * 20 + fr] = lacc[i][r];
  }
  __syncthreads();
  if (wn) {                              // x^2-half partial: add
#pragma unroll
    for (int i = 0; i < 4; ++i)
#pragma unroll
      for (int r = 0; r < 4; ++r)
        red[(wm * 64 + i * 16 + quad * 4 + r) * 20 + fr] += lacc[i][r];
  }
  __syncthreads();
  // FM: C/D col=lane&15 (hl-local), row=quad*4+r; butterfly over l bits (fr&7)
#pragma unroll
  for (int i = 0; i < 4; ++i)
#pragma unroll
    for (int j = 0; j < 4; ++j) {
      const int hin = wn * 8 + j * 2 + (fr >> 3);
#pragma unroll
      for (int r = 0; r < 4; ++r) {
        float v = acc[i][j][r];
        v = v * v;
        v += __shfl_xor(v, 1);
        v += __shfl_xor(v, 2);
        v += __shfl_xor(v, 4);
        if ((lane & 7) == 0)
          red[(wm * 64 + i * 16 + quad * 4 + r) * 20 + hin] += 0.5f * v;
      }
    }
  __syncthreads();
  {
    const int row = tid >> 1, hb = (tid & 1) * 8;   // 8 floats per thread
    const float* rp = red + row * 20 + hb;
    const float* bp = bias + hcol0 + hb;
    float* op = out + (size_t)(row0 + row) * H_DIM + hcol0 + hb;
    f32x4 v0 = *(const f32x4*)(rp);
    f32x4 v1 = *(const f32x4*)(rp + 4);
    f32x4 b0 = *(const f32x4*)(bp);
    f32x4 b1 = *(const f32x4*)(bp + 4);
    *(f32x4*)(op)     = v0 + b0;
    *(f32x4*)(op + 4) = v1 + b1;
  }
}

extern "C" void kernel_launch(void* const* d_in, const int* in_sizes, int n_in,
                              void* d_out, int out_size, void* d_ws, size_t ws_size,
                              hipStream_t stream) {
  const float* x    = (const float*)d_in[0];  // (4096, 512)
  const float* beta = (const float*)d_in[1];  // (1024, 8, 512)
  const float* W    = (const float*)d_in[2];  // (1024, 512)
  const float* bias = (const float*)d_in[3];  // (1024,)
  float* out = (float*)d_out;                 // (4096, 1024)

  uint16_t* xonly = (uint16_t*)d_ws;                        // 4096*512 bf16 = 4 MB
  uint16_t* betab = xonly + (size_t)B_DIM * N_DIM;          // 8192*512 bf16 = 8 MB
  uint16_t* combW = betab + (size_t)HL * N_DIM;             // 1024*1024 bf16 = 2 MB

  const int prep_threads = PREP_T0 + PREP_T1 + PREP_T2;     // 851968
  prep_kernel<<<prep_threads / 256, 256, 0, stream>>>(x, beta, W, xonly, betab, combW);

  // 2048 blocks (64 bx x 32 by), 128x128 tile, 4 waves, dbuf 2-phase pipeline
  fm_kernel<<<2048, 256, 0, stream>>>(xonly, betab, combW, bias, out);
}